// Round 7
// baseline (194.918 us; speedup 1.0000x reference)
//
#include <hip/hip_runtime.h>
#include <hip/hip_fp16.h>
#include <stdint.h>
#include <string.h>

// LightGCN propagation — R21: split R20's s1 into
//   s1a: LDS-heavy ELL build (phases 1-2) + acc0 + segmented list ride-alongs
//   s1b: LDS-free layer-1 spmm over ALL rows from global ELL (full occupancy)
// R20's fused s1 ran the latency-bound gather phase at 3 blocks/CU behind
// the build's 46KB LDS; the gather needs waves, not LDS.
//  K1: single-round LDS-staged counting sort + parallel flat writeout
//      + mark + cvt ride-alongs.
//  spmm2: segmented compact row list + acc1 ride-along.
//  sp3dot: slot-form layer 3 + fused batched dot (paired 16-lane groups).

#define NUM_USERS 100000
#define NUM_ITEMS 50000
#define N_NODES   150000
#define DIM       64
#define N_EDGES   1200000
#define ND        (N_NODES * DIM)
#define NB        4096
#define NSAMP     (2 * NB)

#define ELL_W     24
#define NBKT      640               // buckets
#define RPB       235               // rows per bucket (640*235 = 150400)
#define NROWS_PAD (NBKT * RPB)
#define BCAP      2176              // records per bucket array (mean 1875, +7s)
#define SCAP      13                // K1 LDS staging records per bucket
#define OVF_CAP   512

#define K1_THREADS     1024
#define K1_EDGE_BLOCKS 293          // 293*1024*4 = 1,200,128 >= N_EDGES
#define K1_MARK_BLOCKS 8            // 8*1024 = 8192 = NSAMP
#define K1_CVT_BLOCKS  208          // cvt tail (grid 509 <= 512 slots)

#define S1_THREADS     512
#define S1_ACC_BLOCKS  256          // 32 slots/block * 256 = 8192
#define S1_LST_BLOCKS  256          // segmented list builders
#define EPB            4688         // edges per list block (256*4688 >= N_EDGES)
#define NPB            586          // nodes per list block (256*586 >= N_NODES)

#define L1_ROW_BLOCKS  9376         // 16 rows/block -> 150016 (guarded)

#define NSEG      256
#define SEGCAP    352               // expected 227/seg, sigma~15 -> +8.3 sigma
#define SPB       22                // SEGCAP/16 blocks per segment
#define SEG_BLOCKS (NSEG * SPB)     // 5632
#define OVF2_CAP  2048
#define OVF2_BLOCKS (OVF2_CAP / 16) // 128
#define ACC_BLOCKS  512             // 16 slots/block
#define SP3_BLOCKS  512             // 16 groups/block over 8192 slot-groups

// ---- fp16 pack/unpack helpers (compute in fp32) ---------------------------
__device__ __forceinline__ int h2i(__half2 h) { int r; memcpy(&r, &h, 4); return r; }
__device__ __forceinline__ __half2 i2h(int i) { __half2 h; memcpy(&h, &i, 4); return h; }

__device__ __forceinline__ float4 loadh4(const __half* p) {
    int2 v = *(const int2*)p;
    float2 a = __half22float2(i2h(v.x));
    float2 b = __half22float2(i2h(v.y));
    return make_float4(a.x, a.y, b.x, b.y);
}
__device__ __forceinline__ void storeh4(__half* p, float4 v) {
    int2 o;
    o.x = h2i(__floats2half2_rn(v.x, v.y));
    o.y = h2i(__floats2half2_rn(v.z, v.w));
    *(int2*)p = o;
}
__device__ __forceinline__ float4 f4fma(float v, float4 x, float4 a) {
    a.x += v * x.x; a.y += v * x.y; a.z += v * x.z; a.w += v * x.w;
    return a;
}

// ---------------------------------------------------------------------------
// K1: single-round LDS-staged counting sort + parallel writeout
//     + mark + cvt ride-alongs
// ---------------------------------------------------------------------------
__global__ __launch_bounds__(K1_THREADS)
void k1_kernel(const int* __restrict__ erow,
               const int* __restrict__ ecol,
               const float* __restrict__ evalv,
               const int* __restrict__ users,
               const int* __restrict__ items,
               const float* __restrict__ ue,
               const float* __restrict__ ie,
               int* __restrict__ gtails,
               int2* __restrict__ barr,
               int4* __restrict__ ovf,
               int* __restrict__ ovf_cnt,
               unsigned char* __restrict__ mask3,
               __half* __restrict__ xh) {
    __shared__ int2 stage[NBKT * SCAP];   // 66.6 KB
    __shared__ int  scnt[NBKT];           // 2.5 KB
    __shared__ int  gpos[NBKT];           // 2.5 KB
    if (blockIdx.x < K1_EDGE_BLOCKS) {
        for (int k = threadIdx.x; k < NBKT; k += K1_THREADS) scnt[k] = 0;
        __syncthreads();
        int base = ((int)blockIdx.x * K1_THREADS + (int)threadIdx.x) * 4;
        if (base < N_EDGES) {            // N_EDGES % 4 == 0 -> all 4 valid
            int4   r4 = *(const int4*)(erow + base);
            int4   c4 = *(const int4*)(ecol + base);
            float4 v4 = *(const float4*)(evalv + base);
            int   rr[4] = {r4.x, r4.y, r4.z, r4.w};
            int   cc[4] = {c4.x, c4.y, c4.z, c4.w};
            float vv[4] = {v4.x, v4.y, v4.z, v4.w};
            #pragma unroll
            for (int u = 0; u < 4; ++u) {
                int b    = rr[u] / RPB;
                int rloc = rr[u] - b * RPB;
                int2 rec = make_int2(cc[u] | (rloc << 18), __float_as_int(vv[u]));
                int s = atomicAdd(&scnt[b], 1);
                if (s < SCAP) {
                    stage[b * SCAP + s] = rec;
                } else {
                    // rare: spill straight to global
                    int gp = atomicAdd(&gtails[b], 1);
                    if (gp < BCAP) barr[(size_t)b * BCAP + gp] = rec;
                    else { int q = atomicAdd(ovf_cnt, 1);
                           if (q < OVF_CAP)
                               ovf[q] = make_int4(rr[u], cc[u], __float_as_int(vv[u]), 0); }
                }
            }
        }
        __syncthreads();
        // grab per-bucket global ranges (one atomic per bucket)
        for (int b = threadIdx.x; b < NBKT; b += K1_THREADS) {
            int c = scnt[b];
            c = c < SCAP ? c : SCAP;     // clamp: spilled records already placed
            scnt[b] = c;
            gpos[b] = (c > 0) ? atomicAdd(&gtails[b], c) : 0;
        }
        __syncthreads();
        // flat parallel writeout over (bucket, record) pairs — all 1024 threads
        for (int idx = threadIdx.x; idx < NBKT * SCAP; idx += K1_THREADS) {
            int b = idx / SCAP;
            int i = idx - b * SCAP;
            if (i < scnt[b]) {
                int2 rc = stage[idx];
                int gp = gpos[b] + i;
                if (gp < BCAP) barr[(size_t)b * BCAP + gp] = rc;
                else { int q = atomicAdd(ovf_cnt, 1);
                       if (q < OVF_CAP)
                           ovf[q] = make_int4(b * RPB + (rc.x >> 18),
                                              rc.x & 0x3FFFF, rc.y, 0); }
            }
        }
    } else if (blockIdx.x < K1_EDGE_BLOCKS + K1_MARK_BLOCKS) {
        int i = ((int)blockIdx.x - K1_EDGE_BLOCKS) * K1_THREADS + (int)threadIdx.x;
        if (i < NB)         mask3[users[i]] = 1;
        else if (i < NSAMP) mask3[NUM_USERS + items[i - NB]] = 1;
    } else {
        const int n4  = ND / 4;
        const int nu4 = NUM_USERS * DIM / 4;
        int i = ((int)blockIdx.x - K1_EDGE_BLOCKS - K1_MARK_BLOCKS) * K1_THREADS
                + (int)threadIdx.x;
        const int stride = K1_CVT_BLOCKS * K1_THREADS;
        int2* xh4 = (int2*)xh;
        for (; i < n4; i += stride) {
            float4 v = (i < nu4) ? ((const float4*)ue)[i]
                                 : ((const float4*)ie)[i - nu4];
            int2 o;
            o.x = h2i(__floats2half2_rn(v.x, v.y));
            o.y = h2i(__floats2half2_rn(v.z, v.w));
            xh4[i] = o;
        }
    }
}

// ---------------------------------------------------------------------------
// s1a (512 threads): ELL build (LDS) + cnt-pruned writeout
//     + acc0 + SEGMENTED list-build ride-alongs  (NO spmm here)
// ---------------------------------------------------------------------------
__global__ __launch_bounds__(S1_THREADS)
void s1a_kernel(const int* __restrict__ erow,
                const int* __restrict__ ecol,
                const int* __restrict__ gtails,
                const int2* __restrict__ barr,
                const float* __restrict__ ue,
                const float* __restrict__ ie,
                int* __restrict__ counts,
                int2* __restrict__ ell,
                int4* __restrict__ ovf,
                int* __restrict__ ovf_cnt,
                const unsigned char* __restrict__ mask3,
                int* __restrict__ mask2i,
                int* __restrict__ seg_list,
                int* __restrict__ seg_cnt,
                int* __restrict__ ovf2,
                int* __restrict__ ovf2_cnt,
                const int* __restrict__ users,
                const int* __restrict__ items,
                float* __restrict__ acc_small) {
    __shared__ __align__(16) int2 lell[RPB * ELL_W];   // 45.1 KB
    __shared__ int lcnt[RPB];
    __shared__ int srow[SEGCAP];                       // list blocks
    __shared__ int scnt2;
    const int group = threadIdx.x >> 4;   // 0..31
    const int t     = threadIdx.x & 15;

    if (blockIdx.x < NBKT) {
        const int bkt   = blockIdx.x;
        const int rbase = bkt * RPB;
        // ---- phase 1: build LDS ELL from sorted records ----
        for (int k = threadIdx.x; k < RPB; k += S1_THREADS) lcnt[k] = 0;
        __syncthreads();
        int n = gtails[bkt];
        n = n < BCAP ? n : BCAP;
        for (int e = threadIdx.x; e < n; e += S1_THREADS) {
            int2 rec = barr[(size_t)bkt * BCAP + e];
            int col  = rec.x & 0x3FFFF;
            int rloc = rec.x >> 18;
            int slot = atomicAdd(&lcnt[rloc], 1);
            if (slot < ELL_W)
                lell[rloc * ELL_W + slot] = make_int2(col, rec.y);
            else { int q = atomicAdd(ovf_cnt, 1);
                   if (q < OVF_CAP) ovf[q] = make_int4(rbase + rloc, col, rec.y, 0); }
        }
        __syncthreads();
        // ---- phase 2: cnt-pruned writeout (rows are 192B line-aligned) ----
        int4* g4 = (int4*)(ell + (size_t)rbase * ELL_W);
        const int4* l4 = (const int4*)lell;
        const int PPR = ELL_W / 2;   // 12 int4 pairs per row
        for (int idx = threadIdx.x; idx < RPB * PPR; idx += S1_THREADS) {
            int row = idx / PPR;
            int pr  = idx - row * PPR;
            int c = lcnt[row]; c = c < ELL_W ? c : ELL_W;
            if (pr * 2 < c) g4[idx] = l4[idx];
        }
        for (int k = threadIdx.x; k < RPB; k += S1_THREADS)
            counts[rbase + k] = lcnt[k];
    } else if (blockIdx.x < NBKT + S1_ACC_BLOCKS) {
        // acc0: store layer-0 contribution from the fp32 tables (32 slots/blk)
        const int s = ((int)blockIdx.x - NBKT) * 32 + group;   // < 8192
        const int node = (s < NB) ? users[s] : (NUM_USERS + items[s - NB]);
        const float* p = (node < NUM_USERS) ? ue + (size_t)node * DIM
                                            : ie + (size_t)(node - NUM_USERS) * DIM;
        *(float4*)(acc_small + (size_t)s * DIM + t * 4) = *(const float4*)(p + t * 4);
    } else {
        // segmented list build: dedup via scattered atomicExch, append via
        // LDS counter (no global counter), coalesced segment writeout.
        const int b2 = (int)blockIdx.x - NBKT - S1_ACC_BLOCKS;   // 0..255
        if (threadIdx.x == 0) scnt2 = 0;
        __syncthreads();
        {
            int e0 = b2 * EPB;
            int e1 = e0 + EPB; if (e1 > N_EDGES) e1 = N_EDGES;
            for (int i = e0 + (int)threadIdx.x; i < e1; i += S1_THREADS) {
                if (mask3[erow[i]]) {
                    int c = ecol[i];
                    if (atomicExch(&mask2i[c], 1) == 0) {
                        int p = atomicAdd(&scnt2, 1);
                        if (p < SEGCAP) srow[p] = c;
                        else { int q = atomicAdd(ovf2_cnt, 1);
                               if (q < OVF2_CAP) ovf2[q] = c; }
                    }
                }
            }
        }
        {
            int n0 = b2 * NPB;
            int n1 = n0 + NPB; if (n1 > N_NODES) n1 = N_NODES;
            for (int i = n0 + (int)threadIdx.x; i < n1; i += S1_THREADS) {
                if (mask3[i]) {
                    if (atomicExch(&mask2i[i], 1) == 0) {
                        int p = atomicAdd(&scnt2, 1);
                        if (p < SEGCAP) srow[p] = i;
                        else { int q = atomicAdd(ovf2_cnt, 1);
                               if (q < OVF2_CAP) ovf2[q] = i; }
                    }
                }
            }
        }
        __syncthreads();
        int c = scnt2; c = c < SEGCAP ? c : SEGCAP;
        for (int i = threadIdx.x; i < c; i += S1_THREADS)
            seg_list[b2 * SEGCAP + i] = srow[i];
        if (threadIdx.x == 0) seg_cnt[b2] = c;
    }
}

// ---------------------------------------------------------------------------
// shared gather body (one row per 16-lane group)
// ---------------------------------------------------------------------------
__device__ __forceinline__ void spmm_row(int row, bool active, int t,
                                         const int* __restrict__ counts,
                                         const int2* __restrict__ ell,
                                         const __half* __restrict__ xsrc,
                                         const int* __restrict__ ovf_cnt,
                                         const int4* __restrict__ ovf,
                                         __half* __restrict__ xout) {
    int cnt = 0;
    if (active) {
        cnt = counts[row];
        cnt = cnt < ELL_W ? cnt : ELL_W;
    }
    const int2* ep = ell + (size_t)row * ELL_W;
    float4 a0 = {0,0,0,0}, a1 = {0,0,0,0}, a2 = {0,0,0,0}, a3 = {0,0,0,0};
    int j = 0;
    for (; j + 4 <= cnt; j += 4) {
        int4 cv0 = *(const int4*)(ep + j);
        int4 cv1 = *(const int4*)(ep + j + 2);
        float4 x0 = loadh4(xsrc + (size_t)cv0.x * DIM + t * 4);
        float4 x1 = loadh4(xsrc + (size_t)cv0.z * DIM + t * 4);
        float4 x2 = loadh4(xsrc + (size_t)cv1.x * DIM + t * 4);
        float4 x3 = loadh4(xsrc + (size_t)cv1.z * DIM + t * 4);
        a0 = f4fma(__int_as_float(cv0.y), x0, a0);
        a1 = f4fma(__int_as_float(cv0.w), x1, a1);
        a2 = f4fma(__int_as_float(cv1.y), x2, a2);
        a3 = f4fma(__int_as_float(cv1.w), x3, a3);
    }
    for (; j + 2 <= cnt; j += 2) {
        int4 cv = *(const int4*)(ep + j);
        float4 x0 = loadh4(xsrc + (size_t)cv.x * DIM + t * 4);
        float4 x1 = loadh4(xsrc + (size_t)cv.z * DIM + t * 4);
        a0 = f4fma(__int_as_float(cv.y), x0, a0);
        a1 = f4fma(__int_as_float(cv.w), x1, a1);
    }
    if (j < cnt) {
        int2 cv = ep[j];
        float4 xv = loadh4(xsrc + (size_t)cv.x * DIM + t * 4);
        a0 = f4fma(__int_as_float(cv.y), xv, a0);
    }
    int novf = *ovf_cnt;
    if (novf > 0) {
        novf = novf < OVF_CAP ? novf : OVF_CAP;
        for (int k = 0; k < novf; ++k) {
            int4 o = ovf[k];
            if (active && o.x == row) {
                float4 xv = loadh4(xsrc + (size_t)o.y * DIM + t * 4);
                a0 = f4fma(__int_as_float(o.z), xv, a0);
            }
        }
    }
    if (active) {
        float4 self = loadh4(xsrc + (size_t)row * DIM + t * 4);
        float4 r;
        r.x = 0.2f * self.x + 0.8f * ((a0.x + a1.x) + (a2.x + a3.x));
        r.y = 0.2f * self.y + 0.8f * ((a0.y + a1.y) + (a2.y + a3.y));
        r.z = 0.2f * self.z + 0.8f * ((a0.z + a1.z) + (a2.z + a3.z));
        r.w = 0.2f * self.w + 0.8f * ((a0.w + a1.w) + (a2.w + a3.w));
        storeh4(xout + (size_t)row * DIM + t * 4, r);
    }
}

// ---------------------------------------------------------------------------
// s1b: layer-1 spmm over ALL rows from global ELL — LDS-free, full occupancy
// ---------------------------------------------------------------------------
__global__ __launch_bounds__(256)
void s1b_kernel(const int* __restrict__ counts,
                const int2* __restrict__ ell,
                const __half* __restrict__ xh,
                const int* __restrict__ ovf_cnt,
                const int4* __restrict__ ovf,
                __half* __restrict__ emb_out) {
    const int wid  = threadIdx.x >> 6;
    const int lane = threadIdx.x & 63;
    const int g    = lane >> 4;
    const int t    = lane & 15;
    const int row  = (int)blockIdx.x * 16 + wid * 4 + g;
    spmm_row(row, row < N_NODES, t, counts, ell, xh, ovf_cnt, ovf, emb_out);
}

// ---------------------------------------------------------------------------
// spmm2 (layer 2): segmented compact row list + acc1 ride-along
// ---------------------------------------------------------------------------
__global__ __launch_bounds__(256)
void spmm_kernel(const int* __restrict__ counts,
                 const int2* __restrict__ ell,
                 const __half* __restrict__ xsrc,
                 const int* __restrict__ seg_list,
                 const int* __restrict__ seg_cnt,
                 const int* __restrict__ ovf2,
                 const int* __restrict__ ovf2_cnt,
                 const int* __restrict__ ovf_cnt,
                 const int4* __restrict__ ovf,
                 const int* __restrict__ users,
                 const int* __restrict__ items,
                 float* __restrict__ acc_small,
                 __half* __restrict__ xout) {
    const int wid  = threadIdx.x >> 6;
    const int lane = threadIdx.x & 63;
    const int g    = lane >> 4;
    const int t    = lane & 15;

    if (blockIdx.x < SEG_BLOCKS) {
        const int seg  = blockIdx.x / SPB;
        const int base = ((int)blockIdx.x - seg * SPB) * 16;
        const int cs = seg_cnt[seg];
        if (base >= cs) return;                 // block-uniform early exit
        const int idx = base + wid * 4 + g;
        const bool active = idx < cs;
        const int row = active ? seg_list[seg * SEGCAP + idx] : 0;
        spmm_row(row, active, t, counts, ell, xsrc, ovf_cnt, ovf, xout);
    } else if (blockIdx.x < SEG_BLOCKS + OVF2_BLOCKS) {
        const int b2 = (int)blockIdx.x - SEG_BLOCKS;
        int c2 = *ovf2_cnt; c2 = c2 < OVF2_CAP ? c2 : OVF2_CAP;
        if (b2 * 16 >= c2) return;
        const int idx = b2 * 16 + wid * 4 + g;
        const bool active = idx < c2;
        const int row = active ? ovf2[idx] : 0;
        spmm_row(row, active, t, counts, ell, xsrc, ovf_cnt, ovf, xout);
    } else {
        // acc1 += e1 at sampled slots (xsrc = emb_a)
        const int s = ((int)blockIdx.x - SEG_BLOCKS - OVF2_BLOCKS) * 16 + wid * 4 + g;
        const int node = (s < NB) ? users[s] : (NUM_USERS + items[s - NB]);
        float4 v = loadh4(xsrc + (size_t)node * DIM + t * 4);
        float4* ap = (float4*)(acc_small + (size_t)s * DIM + t * 4);
        float4 a = *ap;
        a.x += v.x; a.y += v.y; a.z += v.z; a.w += v.w;
        *ap = a;
    }
}

// ---------------------------------------------------------------------------
// sp3dot: slot-form layer 3 + fused batched dot.
// ---------------------------------------------------------------------------
__global__ __launch_bounds__(256)
void sp3dot_kernel(const int* __restrict__ counts,
                   const int2* __restrict__ ell,
                   const __half* __restrict__ emb2,
                   const int* __restrict__ ovf_cnt,
                   const int4* __restrict__ ovf,
                   const int* __restrict__ users,
                   const int* __restrict__ items,
                   const float* __restrict__ acc_small,
                   float* __restrict__ out) {
    const int wid  = threadIdx.x >> 6;
    const int lane = threadIdx.x & 63;
    const int g    = lane >> 4;
    const int t    = lane & 15;
    const int G    = blockIdx.x * 16 + wid * 4 + g;       // < 8192
    if (G >= NSAMP) return;
    const int w    = G >> 1;
    const int role = G & 1;                    // 0 = user slot, 1 = item slot
    const int s    = role ? (NB + w) : w;
    const int node = role ? (NUM_USERS + items[w]) : users[w];

    int cnt = counts[node];
    cnt = cnt < ELL_W ? cnt : ELL_W;
    const int2* ep = ell + (size_t)node * ELL_W;
    float4 a0 = {0,0,0,0}, a1 = {0,0,0,0}, a2 = {0,0,0,0}, a3 = {0,0,0,0};
    int j = 0;
    for (; j + 4 <= cnt; j += 4) {
        int4 cv0 = *(const int4*)(ep + j);
        int4 cv1 = *(const int4*)(ep + j + 2);
        float4 x0 = loadh4(emb2 + (size_t)cv0.x * DIM + t * 4);
        float4 x1 = loadh4(emb2 + (size_t)cv0.z * DIM + t * 4);
        float4 x2 = loadh4(emb2 + (size_t)cv1.x * DIM + t * 4);
        float4 x3 = loadh4(emb2 + (size_t)cv1.z * DIM + t * 4);
        a0 = f4fma(__int_as_float(cv0.y), x0, a0);
        a1 = f4fma(__int_as_float(cv0.w), x1, a1);
        a2 = f4fma(__int_as_float(cv1.y), x2, a2);
        a3 = f4fma(__int_as_float(cv1.w), x3, a3);
    }
    for (; j + 2 <= cnt; j += 2) {
        int4 cv = *(const int4*)(ep + j);
        float4 x0 = loadh4(emb2 + (size_t)cv.x * DIM + t * 4);
        float4 x1 = loadh4(emb2 + (size_t)cv.z * DIM + t * 4);
        a0 = f4fma(__int_as_float(cv.y), x0, a0);
        a1 = f4fma(__int_as_float(cv.w), x1, a1);
    }
    if (j < cnt) {
        int2 cv = ep[j];
        float4 xv = loadh4(emb2 + (size_t)cv.x * DIM + t * 4);
        a0 = f4fma(__int_as_float(cv.y), xv, a0);
    }
    int novf = *ovf_cnt;
    if (novf > 0) {
        novf = novf < OVF_CAP ? novf : OVF_CAP;
        for (int k = 0; k < novf; ++k) {
            int4 o = ovf[k];
            if (o.x == node) {
                float4 xv = loadh4(emb2 + (size_t)o.y * DIM + t * 4);
                a0 = f4fma(__int_as_float(o.z), xv, a0);
            }
        }
    }
    float4 self = loadh4(emb2 + (size_t)node * DIM + t * 4);
    float4 a = *(const float4*)(acc_small + (size_t)s * DIM + t * 4);  // e0+e1
    a.x += 1.2f * self.x + 0.8f * ((a0.x + a1.x) + (a2.x + a3.x));
    a.y += 1.2f * self.y + 0.8f * ((a0.y + a1.y) + (a2.y + a3.y));
    a.z += 1.2f * self.z + 0.8f * ((a0.z + a1.z) + (a2.z + a3.z));
    a.w += 1.2f * self.w + 0.8f * ((a0.w + a1.w) + (a2.w + a3.w));
    // fused dot: partner group is lane^16 within the same wave
    float4 b;
    b.x = __shfl_xor(a.x, 16, 64);
    b.y = __shfl_xor(a.y, 16, 64);
    b.z = __shfl_xor(a.z, 16, 64);
    b.w = __shfl_xor(a.w, 16, 64);
    float p = a.x * b.x + a.y * b.y + a.z * b.z + a.w * b.w;
    p += __shfl_xor(p, 1, 64);
    p += __shfl_xor(p, 2, 64);
    p += __shfl_xor(p, 4, 64);
    p += __shfl_xor(p, 8, 64);
    if (role == 0 && t == 0) out[w] = p * 0.0625f;   // (u/4)·(i/4)
}

// ---------------------------------------------------------------------------
extern "C" void kernel_launch(void* const* d_in, const int* in_sizes, int n_in,
                              void* d_out, int out_size, void* d_ws, size_t ws_size,
                              hipStream_t stream) {
    const int*   users = (const int*)  d_in[0];
    const int*   items = (const int*)  d_in[1];
    const int*   erow  = (const int*)  d_in[2];
    const int*   ecol  = (const int*)  d_in[3];
    const float* evalv = (const float*)d_in[4];
    const float* ue    = (const float*)d_in[5];
    const float* ie    = (const float*)d_in[6];
    float* out = (float*)d_out;

    // workspace layout (~104 MB)
    __half* xh        = (__half*)d_ws;                      // 19.2 MB
    __half* emb_a     = xh + ND;                            // 19.2 MB
    __half* emb_b     = emb_a + ND;                         // 19.2 MB
    float*  acc_small = (float*)(emb_b + ND);               // 2 MB
    int2*   barr      = (int2*)(acc_small + NSAMP * DIM);   // 11.1 MB
    int2*   ell       = barr + (size_t)NBKT * BCAP;         // 28.9 MB
    int*    counts    = (int*)(ell + (size_t)NROWS_PAD * ELL_W); // 0.6 MB
    int*    gtails    = counts + NROWS_PAD;                 // NBKT
    int*    ovf_cnt   = gtails + NBKT;                      // 1
    int4*   ovf       = (int4*)(((uintptr_t)(ovf_cnt + 1) + 15) & ~(uintptr_t)15);
    unsigned char* mask3 = (unsigned char*)(ovf + OVF_CAP); // N_NODES
    int*    mask2i    = (int*)(((uintptr_t)(mask3 + N_NODES) + 15) & ~(uintptr_t)15);
    int*    seg_cnt   = mask2i + N_NODES;                   // NSEG
    int*    ovf2_cnt  = seg_cnt + NSEG;                     // 1
    // ---- end of zero region ----
    int*    ovf2      = ovf2_cnt + 1;                       // OVF2_CAP
    int*    seg_list  = ovf2 + OVF2_CAP;                    // NSEG*SEGCAP

    // zero gtails | ovf_cnt | ovf | mask3 | mask2i | seg_cnt | ovf2_cnt
    size_t zbytes = (size_t)((unsigned char*)(ovf2_cnt + 1) - (unsigned char*)gtails);
    hipMemsetAsync(gtails, 0, zbytes, stream);

    k1_kernel<<<K1_EDGE_BLOCKS + K1_MARK_BLOCKS + K1_CVT_BLOCKS, K1_THREADS, 0, stream>>>(
        erow, ecol, evalv, users, items, ue, ie,
        gtails, barr, ovf, ovf_cnt, mask3, xh);

    // s1a: ELL build + pruned writeout + acc0 + segmented list
    s1a_kernel<<<NBKT + S1_ACC_BLOCKS + S1_LST_BLOCKS, S1_THREADS, 0, stream>>>(
        erow, ecol, gtails, barr, ue, ie, counts, ell, ovf, ovf_cnt,
        mask3, mask2i, seg_list, seg_cnt, ovf2, ovf2_cnt,
        users, items, acc_small);

    // s1b: layer-1 spmm over all rows (LDS-free, full occupancy)
    s1b_kernel<<<L1_ROW_BLOCKS, 256, 0, stream>>>(
        counts, ell, xh, ovf_cnt, ovf, emb_a);

    // layer 2 (segmented list) + acc1 (from emb_a)
    spmm_kernel<<<SEG_BLOCKS + OVF2_BLOCKS + ACC_BLOCKS, 256, 0, stream>>>(
        counts, ell, emb_a, seg_list, seg_cnt, ovf2, ovf2_cnt, ovf_cnt, ovf,
        users, items, acc_small, emb_b);

    // layer 3 slot-form + fused dot
    sp3dot_kernel<<<SP3_BLOCKS, 256, 0, stream>>>(
        counts, ell, emb_b, ovf_cnt, ovf, users, items, acc_small, out);
}

// Round 8
// 184.492 us; speedup vs baseline: 1.0565x; 1.0565x over previous
//
#include <hip/hip_runtime.h>
#include <hip/hip_fp16.h>
#include <stdint.h>
#include <string.h>

// LightGCN propagation — R22: R17 base + IN-BUCKET segment-list build.
//  The layer-2 active-row list is built inside s1's bucket blocks from the
//  LDS-resident ELL (marked row -> its cols), deleting R17's 1024 expand +
//  293 copy ride-along blocks (and their 9.6MB edge re-read). spmm2 then
//  walks the packed segment list (R20-validated). Node count stays 5.
//  K1: single-round LDS-staged counting sort + parallel flat writeout
//      + mark + cvt ride-alongs.
//  s1: per-bucket ELL build (LDS) -> cnt-pruned writeout -> in-bucket
//      list build -> layer-1 spmm from LDS; acc0 ride-along (+ovf backstop).
//  spmm2: segmented compact row list + acc1 ride-along.
//  sp3dot: slot-form layer 3 + fused batched dot (paired 16-lane groups).

#define NUM_USERS 100000
#define NUM_ITEMS 50000
#define N_NODES   150000
#define DIM       64
#define N_EDGES   1200000
#define ND        (N_NODES * DIM)
#define NB        4096
#define NSAMP     (2 * NB)

#define ELL_W     24
#define NBKT      640               // buckets == segments
#define RPB       235               // rows per bucket (640*235 = 150400)
#define NROWS_PAD (NBKT * RPB)
#define BCAP      2176              // records per bucket array (mean 1875, +7s)
#define SCAP      13                // K1 LDS staging records per bucket
#define OVF_CAP   512

#define K1_THREADS     1024
#define K1_EDGE_BLOCKS 293          // 293*1024*4 = 1,200,128 >= N_EDGES
#define K1_MARK_BLOCKS 8            // 8*1024 = 8192 = NSAMP
#define K1_CVT_BLOCKS  208          // cvt tail (grid 509 <= 512 slots)

#define S1_THREADS     512
#define S1_ACC_BLOCKS  256          // 32 slots/block * 256 = 8192

#define NSEG      NBKT              // one segment per bucket
#define SEGCAP    320               // mean ~95/seg; P(>320) < 1e-8 + backstop
#define SPB       20                // SEGCAP/16 blocks per segment
#define SEG_BLOCKS (NSEG * SPB)     // 12800
#define OVF2_CAP  4096
#define OVF2_BLOCKS (OVF2_CAP / 16) // 256
#define ACC_BLOCKS  512             // 16 slots/block
#define SP3_BLOCKS  512             // 16 groups/block over 8192 slot-groups

// ---- fp16 pack/unpack helpers (compute in fp32) ---------------------------
__device__ __forceinline__ int h2i(__half2 h) { int r; memcpy(&r, &h, 4); return r; }
__device__ __forceinline__ __half2 i2h(int i) { __half2 h; memcpy(&h, &i, 4); return h; }

__device__ __forceinline__ float4 loadh4(const __half* p) {
    int2 v = *(const int2*)p;
    float2 a = __half22float2(i2h(v.x));
    float2 b = __half22float2(i2h(v.y));
    return make_float4(a.x, a.y, b.x, b.y);
}
__device__ __forceinline__ void storeh4(__half* p, float4 v) {
    int2 o;
    o.x = h2i(__floats2half2_rn(v.x, v.y));
    o.y = h2i(__floats2half2_rn(v.z, v.w));
    *(int2*)p = o;
}
__device__ __forceinline__ float4 f4fma(float v, float4 x, float4 a) {
    a.x += v * x.x; a.y += v * x.y; a.z += v * x.z; a.w += v * x.w;
    return a;
}

// ---------------------------------------------------------------------------
// K1: single-round LDS-staged counting sort + parallel writeout
//     + mark + cvt ride-alongs   (identical to R17)
// ---------------------------------------------------------------------------
__global__ __launch_bounds__(K1_THREADS)
void k1_kernel(const int* __restrict__ erow,
               const int* __restrict__ ecol,
               const float* __restrict__ evalv,
               const int* __restrict__ users,
               const int* __restrict__ items,
               const float* __restrict__ ue,
               const float* __restrict__ ie,
               int* __restrict__ gtails,
               int2* __restrict__ barr,
               int4* __restrict__ ovf,
               int* __restrict__ ovf_cnt,
               unsigned char* __restrict__ mask3,
               __half* __restrict__ xh) {
    __shared__ int2 stage[NBKT * SCAP];   // 66.6 KB
    __shared__ int  scnt[NBKT];           // 2.5 KB
    __shared__ int  gpos[NBKT];           // 2.5 KB
    if (blockIdx.x < K1_EDGE_BLOCKS) {
        for (int k = threadIdx.x; k < NBKT; k += K1_THREADS) scnt[k] = 0;
        __syncthreads();
        int base = ((int)blockIdx.x * K1_THREADS + (int)threadIdx.x) * 4;
        if (base < N_EDGES) {            // N_EDGES % 4 == 0 -> all 4 valid
            int4   r4 = *(const int4*)(erow + base);
            int4   c4 = *(const int4*)(ecol + base);
            float4 v4 = *(const float4*)(evalv + base);
            int   rr[4] = {r4.x, r4.y, r4.z, r4.w};
            int   cc[4] = {c4.x, c4.y, c4.z, c4.w};
            float vv[4] = {v4.x, v4.y, v4.z, v4.w};
            #pragma unroll
            for (int u = 0; u < 4; ++u) {
                int b    = rr[u] / RPB;
                int rloc = rr[u] - b * RPB;
                int2 rec = make_int2(cc[u] | (rloc << 18), __float_as_int(vv[u]));
                int s = atomicAdd(&scnt[b], 1);
                if (s < SCAP) {
                    stage[b * SCAP + s] = rec;
                } else {
                    // rare: spill straight to global
                    int gp = atomicAdd(&gtails[b], 1);
                    if (gp < BCAP) barr[(size_t)b * BCAP + gp] = rec;
                    else { int q = atomicAdd(ovf_cnt, 1);
                           if (q < OVF_CAP)
                               ovf[q] = make_int4(rr[u], cc[u], __float_as_int(vv[u]), 0); }
                }
            }
        }
        __syncthreads();
        // grab per-bucket global ranges (one atomic per bucket)
        for (int b = threadIdx.x; b < NBKT; b += K1_THREADS) {
            int c = scnt[b];
            c = c < SCAP ? c : SCAP;     // clamp: spilled records already placed
            scnt[b] = c;
            gpos[b] = (c > 0) ? atomicAdd(&gtails[b], c) : 0;
        }
        __syncthreads();
        // flat parallel writeout over (bucket, record) pairs — all 1024 threads
        for (int idx = threadIdx.x; idx < NBKT * SCAP; idx += K1_THREADS) {
            int b = idx / SCAP;
            int i = idx - b * SCAP;
            if (i < scnt[b]) {
                int2 rc = stage[idx];
                int gp = gpos[b] + i;
                if (gp < BCAP) barr[(size_t)b * BCAP + gp] = rc;
                else { int q = atomicAdd(ovf_cnt, 1);
                       if (q < OVF_CAP)
                           ovf[q] = make_int4(b * RPB + (rc.x >> 18),
                                              rc.x & 0x3FFFF, rc.y, 0); }
            }
        }
    } else if (blockIdx.x < K1_EDGE_BLOCKS + K1_MARK_BLOCKS) {
        int i = ((int)blockIdx.x - K1_EDGE_BLOCKS) * K1_THREADS + (int)threadIdx.x;
        if (i < NB)         mask3[users[i]] = 1;
        else if (i < NSAMP) mask3[NUM_USERS + items[i - NB]] = 1;
    } else {
        const int n4  = ND / 4;
        const int nu4 = NUM_USERS * DIM / 4;
        int i = ((int)blockIdx.x - K1_EDGE_BLOCKS - K1_MARK_BLOCKS) * K1_THREADS
                + (int)threadIdx.x;
        const int stride = K1_CVT_BLOCKS * K1_THREADS;
        int2* xh4 = (int2*)xh;
        for (; i < n4; i += stride) {
            float4 v = (i < nu4) ? ((const float4*)ue)[i]
                                 : ((const float4*)ie)[i - nu4];
            int2 o;
            o.x = h2i(__floats2half2_rn(v.x, v.y));
            o.y = h2i(__floats2half2_rn(v.z, v.w));
            xh4[i] = o;
        }
    }
}

// ---------------------------------------------------------------------------
// s1 (512 threads): ELL build (LDS) + cnt-pruned writeout + IN-BUCKET
//     segment-list build + layer-1 spmm from LDS + acc0 (+ovf backstop)
// ---------------------------------------------------------------------------
__global__ __launch_bounds__(S1_THREADS)
void s1_kernel(const int* __restrict__ gtails,
               const int2* __restrict__ barr,
               const __half* __restrict__ xh,
               const float* __restrict__ ue,
               const float* __restrict__ ie,
               int* __restrict__ counts,
               int2* __restrict__ ell,
               int4* __restrict__ ovf,
               int* __restrict__ ovf_cnt,
               const unsigned char* __restrict__ mask3,
               int* __restrict__ mask2i,
               int* __restrict__ seg_list,
               int* __restrict__ seg_cnt,
               int* __restrict__ ovf2,
               int* __restrict__ ovf2_cnt,
               const int* __restrict__ users,
               const int* __restrict__ items,
               float* __restrict__ acc_small,
               __half* __restrict__ emb_out) {
    __shared__ __align__(16) int2 lell[RPB * ELL_W];   // 45.1 KB
    __shared__ int lcnt[RPB];                          // 0.9 KB
    __shared__ int srow[SEGCAP];                       // 1.25 KB
    __shared__ int scnt2;
    const int group = threadIdx.x >> 4;   // 0..31
    const int t     = threadIdx.x & 15;

    if (blockIdx.x < NBKT) {
        const int bkt   = blockIdx.x;
        const int rbase = bkt * RPB;
        // ---- phase 1: build LDS ELL from sorted records ----
        for (int k = threadIdx.x; k < RPB; k += S1_THREADS) lcnt[k] = 0;
        if (threadIdx.x == 0) scnt2 = 0;
        __syncthreads();
        int n = gtails[bkt];
        n = n < BCAP ? n : BCAP;
        for (int e = threadIdx.x; e < n; e += S1_THREADS) {
            int2 rec = barr[(size_t)bkt * BCAP + e];
            int col  = rec.x & 0x3FFFF;
            int rloc = rec.x >> 18;
            int slot = atomicAdd(&lcnt[rloc], 1);
            if (slot < ELL_W)
                lell[rloc * ELL_W + slot] = make_int2(col, rec.y);
            else { int q = atomicAdd(ovf_cnt, 1);
                   if (q < OVF_CAP) ovf[q] = make_int4(rbase + rloc, col, rec.y, 0); }
        }
        __syncthreads();
        // ---- phase 2: cnt-pruned writeout (rows are 192B line-aligned) ----
        {
            int4* g4 = (int4*)(ell + (size_t)rbase * ELL_W);
            const int4* l4 = (const int4*)lell;
            const int PPR = ELL_W / 2;   // 12 int4 pairs per row
            for (int idx = threadIdx.x; idx < RPB * PPR; idx += S1_THREADS) {
                int row = idx / PPR;
                int pr  = idx - row * PPR;
                int c = lcnt[row]; c = c < ELL_W ? c : ELL_W;
                if (pr * 2 < c) g4[idx] = l4[idx];
            }
            for (int k = threadIdx.x; k < RPB; k += S1_THREADS)
                counts[rbase + k] = lcnt[k];
        }
        // ---- phase 2.5: in-bucket list build from LDS ELL ----
        // (row itself at k==0, its ELL cols at k-1; dedup via mask2i)
        for (int idx = threadIdx.x; idx < RPB * (ELL_W + 1); idx += S1_THREADS) {
            int rloc = idx / (ELL_W + 1);
            int k    = idx - rloc * (ELL_W + 1);
            int row  = rbase + rloc;
            if (row >= N_NODES || !mask3[row]) continue;
            int target;
            if (k == 0) target = row;
            else {
                int c = lcnt[rloc]; c = c < ELL_W ? c : ELL_W;
                if (k - 1 >= c) continue;
                target = lell[rloc * ELL_W + (k - 1)].x;
            }
            if (atomicExch(&mask2i[target], 1) == 0) {
                int p = atomicAdd(&scnt2, 1);
                if (p < SEGCAP) srow[p] = target;
                else { int q = atomicAdd(ovf2_cnt, 1);
                       if (q < OVF2_CAP) ovf2[q] = target; }
            }
        }
        __syncthreads();
        {
            int c = scnt2; c = c < SEGCAP ? c : SEGCAP;
            for (int i = threadIdx.x; i < c; i += S1_THREADS)
                seg_list[bkt * SEGCAP + i] = srow[i];
            if (threadIdx.x == 0) seg_cnt[bkt] = c;
        }
        // ---- phase 3: layer-1 spmm reading ELL from LDS ----
        int novf = *ovf_cnt;
        novf = novf < OVF_CAP ? novf : OVF_CAP;
        for (int k = 0; k < 8; ++k) {                 // 32 groups x 8 = 256 >= 235
            int rloc = group + 32 * k;
            if (rloc >= RPB) break;
            int row = rbase + rloc;
            if (row >= N_NODES) continue;
            int cnt = lcnt[rloc];
            cnt = cnt < ELL_W ? cnt : ELL_W;
            const int2* ep = &lell[rloc * ELL_W];
            float4 a0 = {0,0,0,0}, a1 = {0,0,0,0}, a2 = {0,0,0,0}, a3 = {0,0,0,0};
            int j = 0;
            for (; j + 4 <= cnt; j += 4) {
                int4 cv0 = *(const int4*)(ep + j);
                int4 cv1 = *(const int4*)(ep + j + 2);
                float4 x0 = loadh4(xh + (size_t)cv0.x * DIM + t * 4);
                float4 x1 = loadh4(xh + (size_t)cv0.z * DIM + t * 4);
                float4 x2 = loadh4(xh + (size_t)cv1.x * DIM + t * 4);
                float4 x3 = loadh4(xh + (size_t)cv1.z * DIM + t * 4);
                a0 = f4fma(__int_as_float(cv0.y), x0, a0);
                a1 = f4fma(__int_as_float(cv0.w), x1, a1);
                a2 = f4fma(__int_as_float(cv1.y), x2, a2);
                a3 = f4fma(__int_as_float(cv1.w), x3, a3);
            }
            for (; j + 2 <= cnt; j += 2) {
                int4 cv = *(const int4*)(ep + j);
                float4 x0 = loadh4(xh + (size_t)cv.x * DIM + t * 4);
                float4 x1 = loadh4(xh + (size_t)cv.z * DIM + t * 4);
                a0 = f4fma(__int_as_float(cv.y), x0, a0);
                a1 = f4fma(__int_as_float(cv.w), x1, a1);
            }
            if (j < cnt) {
                int2 cv = ep[j];
                float4 xv = loadh4(xh + (size_t)cv.x * DIM + t * 4);
                a0 = f4fma(__int_as_float(cv.y), xv, a0);
            }
            for (int q = 0; q < novf; ++q) {
                int4 o = ovf[q];
                if (o.x == row) {
                    float4 xv = loadh4(xh + (size_t)o.y * DIM + t * 4);
                    a0 = f4fma(__int_as_float(o.z), xv, a0);
                }
            }
            float4 self = loadh4(xh + (size_t)row * DIM + t * 4);
            float4 r;
            r.x = 0.2f * self.x + 0.8f * ((a0.x + a1.x) + (a2.x + a3.x));
            r.y = 0.2f * self.y + 0.8f * ((a0.y + a1.y) + (a2.y + a3.y));
            r.z = 0.2f * self.z + 0.8f * ((a0.z + a1.z) + (a2.z + a3.z));
            r.w = 0.2f * self.w + 0.8f * ((a0.w + a1.w) + (a2.w + a3.w));
            storeh4(emb_out + (size_t)row * DIM + t * 4, r);
        }
    } else {
        // acc0: store layer-0 contribution from the fp32 tables (32 slots/blk)
        const int b = (int)blockIdx.x - NBKT;
        const int s = b * 32 + group;   // < 8192
        const int node = (s < NB) ? users[s] : (NUM_USERS + items[s - NB]);
        const float* p = (node < NUM_USERS) ? ue + (size_t)node * DIM
                                            : ie + (size_t)(node - NUM_USERS) * DIM;
        *(float4*)(acc_small + (size_t)s * DIM + t * 4) = *(const float4*)(p + t * 4);
        // ovf backstop (block 0 only): cols of ELL-spilled edges of marked rows
        if (b == 0) {
            int novf = *ovf_cnt;
            novf = novf < OVF_CAP ? novf : OVF_CAP;
            for (int k = threadIdx.x; k < novf; k += S1_THREADS) {
                int4 o = ovf[k];
                if (mask3[o.x]) {
                    if (atomicExch(&mask2i[o.y], 1) == 0) {
                        int q = atomicAdd(ovf2_cnt, 1);
                        if (q < OVF2_CAP) ovf2[q] = o.y;
                    }
                }
            }
        }
    }
}

// ---------------------------------------------------------------------------
// shared gather body (one row per 16-lane group)
// ---------------------------------------------------------------------------
__device__ __forceinline__ void spmm_row(int row, bool active, int t,
                                         const int* __restrict__ counts,
                                         const int2* __restrict__ ell,
                                         const __half* __restrict__ xsrc,
                                         const int* __restrict__ ovf_cnt,
                                         const int4* __restrict__ ovf,
                                         __half* __restrict__ xout) {
    int cnt = 0;
    if (active) {
        cnt = counts[row];
        cnt = cnt < ELL_W ? cnt : ELL_W;
    }
    const int2* ep = ell + (size_t)row * ELL_W;
    float4 a0 = {0,0,0,0}, a1 = {0,0,0,0}, a2 = {0,0,0,0}, a3 = {0,0,0,0};
    int j = 0;
    for (; j + 4 <= cnt; j += 4) {
        int4 cv0 = *(const int4*)(ep + j);
        int4 cv1 = *(const int4*)(ep + j + 2);
        float4 x0 = loadh4(xsrc + (size_t)cv0.x * DIM + t * 4);
        float4 x1 = loadh4(xsrc + (size_t)cv0.z * DIM + t * 4);
        float4 x2 = loadh4(xsrc + (size_t)cv1.x * DIM + t * 4);
        float4 x3 = loadh4(xsrc + (size_t)cv1.z * DIM + t * 4);
        a0 = f4fma(__int_as_float(cv0.y), x0, a0);
        a1 = f4fma(__int_as_float(cv0.w), x1, a1);
        a2 = f4fma(__int_as_float(cv1.y), x2, a2);
        a3 = f4fma(__int_as_float(cv1.w), x3, a3);
    }
    for (; j + 2 <= cnt; j += 2) {
        int4 cv = *(const int4*)(ep + j);
        float4 x0 = loadh4(xsrc + (size_t)cv.x * DIM + t * 4);
        float4 x1 = loadh4(xsrc + (size_t)cv.z * DIM + t * 4);
        a0 = f4fma(__int_as_float(cv.y), x0, a0);
        a1 = f4fma(__int_as_float(cv.w), x1, a1);
    }
    if (j < cnt) {
        int2 cv = ep[j];
        float4 xv = loadh4(xsrc + (size_t)cv.x * DIM + t * 4);
        a0 = f4fma(__int_as_float(cv.y), xv, a0);
    }
    int novf = *ovf_cnt;
    if (novf > 0) {
        novf = novf < OVF_CAP ? novf : OVF_CAP;
        for (int k = 0; k < novf; ++k) {
            int4 o = ovf[k];
            if (active && o.x == row) {
                float4 xv = loadh4(xsrc + (size_t)o.y * DIM + t * 4);
                a0 = f4fma(__int_as_float(o.z), xv, a0);
            }
        }
    }
    if (active) {
        float4 self = loadh4(xsrc + (size_t)row * DIM + t * 4);
        float4 r;
        r.x = 0.2f * self.x + 0.8f * ((a0.x + a1.x) + (a2.x + a3.x));
        r.y = 0.2f * self.y + 0.8f * ((a0.y + a1.y) + (a2.y + a3.y));
        r.z = 0.2f * self.z + 0.8f * ((a0.z + a1.z) + (a2.z + a3.z));
        r.w = 0.2f * self.w + 0.8f * ((a0.w + a1.w) + (a2.w + a3.w));
        storeh4(xout + (size_t)row * DIM + t * 4, r);
    }
}

// ---------------------------------------------------------------------------
// spmm2 (layer 2): segmented compact row list + acc1 ride-along
// ---------------------------------------------------------------------------
__global__ __launch_bounds__(256)
void spmm_kernel(const int* __restrict__ counts,
                 const int2* __restrict__ ell,
                 const __half* __restrict__ xsrc,
                 const int* __restrict__ seg_list,
                 const int* __restrict__ seg_cnt,
                 const int* __restrict__ ovf2,
                 const int* __restrict__ ovf2_cnt,
                 const int* __restrict__ ovf_cnt,
                 const int4* __restrict__ ovf,
                 const int* __restrict__ users,
                 const int* __restrict__ items,
                 float* __restrict__ acc_small,
                 __half* __restrict__ xout) {
    const int wid  = threadIdx.x >> 6;
    const int lane = threadIdx.x & 63;
    const int g    = lane >> 4;
    const int t    = lane & 15;

    if (blockIdx.x < SEG_BLOCKS) {
        const int seg  = blockIdx.x / SPB;
        const int base = ((int)blockIdx.x - seg * SPB) * 16;
        const int cs = seg_cnt[seg];
        if (base >= cs) return;                 // block-uniform early exit
        const int idx = base + wid * 4 + g;
        const bool active = idx < cs;
        const int row = active ? seg_list[seg * SEGCAP + idx] : 0;
        spmm_row(row, active, t, counts, ell, xsrc, ovf_cnt, ovf, xout);
    } else if (blockIdx.x < SEG_BLOCKS + OVF2_BLOCKS) {
        const int b2 = (int)blockIdx.x - SEG_BLOCKS;
        int c2 = *ovf2_cnt; c2 = c2 < OVF2_CAP ? c2 : OVF2_CAP;
        if (b2 * 16 >= c2) return;
        const int idx = b2 * 16 + wid * 4 + g;
        const bool active = idx < c2;
        const int row = active ? ovf2[idx] : 0;
        spmm_row(row, active, t, counts, ell, xsrc, ovf_cnt, ovf, xout);
    } else {
        // acc1 += e1 at sampled slots (xsrc = emb_a)
        const int s = ((int)blockIdx.x - SEG_BLOCKS - OVF2_BLOCKS) * 16 + wid * 4 + g;
        const int node = (s < NB) ? users[s] : (NUM_USERS + items[s - NB]);
        float4 v = loadh4(xsrc + (size_t)node * DIM + t * 4);
        float4* ap = (float4*)(acc_small + (size_t)s * DIM + t * 4);
        float4 a = *ap;
        a.x += v.x; a.y += v.y; a.z += v.z; a.w += v.w;
        *ap = a;
    }
}

// ---------------------------------------------------------------------------
// sp3dot: slot-form layer 3 + fused batched dot.
//   Pair (user slot w, item slot NB+w) sit in adjacent 16-lane groups of the
//   same wave -> partner acc via shfl_xor(16), reduce via shfl_xor(1,2,4,8).
// ---------------------------------------------------------------------------
__global__ __launch_bounds__(256)
void sp3dot_kernel(const int* __restrict__ counts,
                   const int2* __restrict__ ell,
                   const __half* __restrict__ emb2,
                   const int* __restrict__ ovf_cnt,
                   const int4* __restrict__ ovf,
                   const int* __restrict__ users,
                   const int* __restrict__ items,
                   const float* __restrict__ acc_small,
                   float* __restrict__ out) {
    const int wid  = threadIdx.x >> 6;
    const int lane = threadIdx.x & 63;
    const int g    = lane >> 4;
    const int t    = lane & 15;
    const int G    = blockIdx.x * 16 + wid * 4 + g;       // < 8192
    if (G >= NSAMP) return;
    const int w    = G >> 1;
    const int role = G & 1;                    // 0 = user slot, 1 = item slot
    const int s    = role ? (NB + w) : w;
    const int node = role ? (NUM_USERS + items[w]) : users[w];

    int cnt = counts[node];
    cnt = cnt < ELL_W ? cnt : ELL_W;
    const int2* ep = ell + (size_t)node * ELL_W;
    float4 a0 = {0,0,0,0}, a1 = {0,0,0,0}, a2 = {0,0,0,0}, a3 = {0,0,0,0};
    int j = 0;
    for (; j + 4 <= cnt; j += 4) {
        int4 cv0 = *(const int4*)(ep + j);
        int4 cv1 = *(const int4*)(ep + j + 2);
        float4 x0 = loadh4(emb2 + (size_t)cv0.x * DIM + t * 4);
        float4 x1 = loadh4(emb2 + (size_t)cv0.z * DIM + t * 4);
        float4 x2 = loadh4(emb2 + (size_t)cv1.x * DIM + t * 4);
        float4 x3 = loadh4(emb2 + (size_t)cv1.z * DIM + t * 4);
        a0 = f4fma(__int_as_float(cv0.y), x0, a0);
        a1 = f4fma(__int_as_float(cv0.w), x1, a1);
        a2 = f4fma(__int_as_float(cv1.y), x2, a2);
        a3 = f4fma(__int_as_float(cv1.w), x3, a3);
    }
    for (; j + 2 <= cnt; j += 2) {
        int4 cv = *(const int4*)(ep + j);
        float4 x0 = loadh4(emb2 + (size_t)cv.x * DIM + t * 4);
        float4 x1 = loadh4(emb2 + (size_t)cv.z * DIM + t * 4);
        a0 = f4fma(__int_as_float(cv.y), x0, a0);
        a1 = f4fma(__int_as_float(cv.w), x1, a1);
    }
    if (j < cnt) {
        int2 cv = ep[j];
        float4 xv = loadh4(emb2 + (size_t)cv.x * DIM + t * 4);
        a0 = f4fma(__int_as_float(cv.y), xv, a0);
    }
    int novf = *ovf_cnt;
    if (novf > 0) {
        novf = novf < OVF_CAP ? novf : OVF_CAP;
        for (int k = 0; k < novf; ++k) {
            int4 o = ovf[k];
            if (o.x == node) {
                float4 xv = loadh4(emb2 + (size_t)o.y * DIM + t * 4);
                a0 = f4fma(__int_as_float(o.z), xv, a0);
            }
        }
    }
    float4 self = loadh4(emb2 + (size_t)node * DIM + t * 4);
    float4 a = *(const float4*)(acc_small + (size_t)s * DIM + t * 4);  // e0+e1
    a.x += 1.2f * self.x + 0.8f * ((a0.x + a1.x) + (a2.x + a3.x));
    a.y += 1.2f * self.y + 0.8f * ((a0.y + a1.y) + (a2.y + a3.y));
    a.z += 1.2f * self.z + 0.8f * ((a0.z + a1.z) + (a2.z + a3.z));
    a.w += 1.2f * self.w + 0.8f * ((a0.w + a1.w) + (a2.w + a3.w));
    // fused dot: partner group is lane^16 within the same wave
    float4 b;
    b.x = __shfl_xor(a.x, 16, 64);
    b.y = __shfl_xor(a.y, 16, 64);
    b.z = __shfl_xor(a.z, 16, 64);
    b.w = __shfl_xor(a.w, 16, 64);
    float p = a.x * b.x + a.y * b.y + a.z * b.z + a.w * b.w;
    p += __shfl_xor(p, 1, 64);
    p += __shfl_xor(p, 2, 64);
    p += __shfl_xor(p, 4, 64);
    p += __shfl_xor(p, 8, 64);
    if (role == 0 && t == 0) out[w] = p * 0.0625f;   // (u/4)·(i/4)
}

// ---------------------------------------------------------------------------
extern "C" void kernel_launch(void* const* d_in, const int* in_sizes, int n_in,
                              void* d_out, int out_size, void* d_ws, size_t ws_size,
                              hipStream_t stream) {
    const int*   users = (const int*)  d_in[0];
    const int*   items = (const int*)  d_in[1];
    const int*   erow  = (const int*)  d_in[2];
    const int*   ecol  = (const int*)  d_in[3];
    const float* evalv = (const float*)d_in[4];
    const float* ue    = (const float*)d_in[5];
    const float* ie    = (const float*)d_in[6];
    float* out = (float*)d_out;

    // workspace layout (~105 MB)
    __half* xh        = (__half*)d_ws;                      // 19.2 MB
    __half* emb_a     = xh + ND;                            // 19.2 MB
    __half* emb_b     = emb_a + ND;                         // 19.2 MB
    float*  acc_small = (float*)(emb_b + ND);               // 2 MB
    int2*   barr      = (int2*)(acc_small + NSAMP * DIM);   // 11.1 MB
    int2*   ell       = barr + (size_t)NBKT * BCAP;         // 28.9 MB
    int*    counts    = (int*)(ell + (size_t)NROWS_PAD * ELL_W); // 0.6 MB
    int*    gtails    = counts + NROWS_PAD;                 // NBKT
    int*    ovf_cnt   = gtails + NBKT;                      // 1
    int4*   ovf       = (int4*)(((uintptr_t)(ovf_cnt + 1) + 15) & ~(uintptr_t)15);
    unsigned char* mask3 = (unsigned char*)(ovf + OVF_CAP); // N_NODES
    int*    mask2i    = (int*)(((uintptr_t)(mask3 + N_NODES) + 15) & ~(uintptr_t)15);
    int*    seg_cnt   = mask2i + N_NODES;                   // NSEG
    int*    ovf2_cnt  = seg_cnt + NSEG;                     // 1
    // ---- end of zero region ----
    int*    ovf2      = ovf2_cnt + 1;                       // OVF2_CAP
    int*    seg_list  = ovf2 + OVF2_CAP;                    // NSEG*SEGCAP

    // zero gtails | ovf_cnt | ovf | mask3 | mask2i | seg_cnt | ovf2_cnt
    size_t zbytes = (size_t)((unsigned char*)(ovf2_cnt + 1) - (unsigned char*)gtails);
    hipMemsetAsync(gtails, 0, zbytes, stream);

    k1_kernel<<<K1_EDGE_BLOCKS + K1_MARK_BLOCKS + K1_CVT_BLOCKS, K1_THREADS, 0, stream>>>(
        erow, ecol, evalv, users, items, ue, ie,
        gtails, barr, ovf, ovf_cnt, mask3, xh);

    // s1: ELL build + pruned writeout + in-bucket list + layer-1 spmm + acc0
    s1_kernel<<<NBKT + S1_ACC_BLOCKS, S1_THREADS, 0, stream>>>(
        gtails, barr, xh, ue, ie, counts, ell, ovf, ovf_cnt,
        mask3, mask2i, seg_list, seg_cnt, ovf2, ovf2_cnt,
        users, items, acc_small, emb_a);

    // layer 2 (segmented list) + acc1 (from emb_a)
    spmm_kernel<<<SEG_BLOCKS + OVF2_BLOCKS + ACC_BLOCKS, 256, 0, stream>>>(
        counts, ell, emb_a, seg_list, seg_cnt, ovf2, ovf2_cnt, ovf_cnt, ovf,
        users, items, acc_small, emb_b);

    // layer 3 slot-form + fused dot
    sp3dot_kernel<<<SP3_BLOCKS, 256, 0, stream>>>(
        counts, ell, emb_b, ovf_cnt, ovf, users, items, acc_small, out);
}